// Round 15
// baseline (239.776 us; speedup 1.0000x reference)
//
#include <hip/hip_runtime.h>
#include <hip/hip_bf16.h>

// GCN encoder: 2x GCNConv (sym-norm, self-loops) + ReLU + row L2 normalize.
// N=50000, E=800000, IN=128, HID=256, OUT=256.
// Aggregate-first + phase-sorted edata + PERSISTENT-GRID aggs (2048 blocks,
// wave-strided nodes: full 32-wave/CU residency, synchronized phase sweep).
// BM=128 512-thread MFMA GEMMs with fused epilogues.

#define NNODE 50000
#define FDIM 256
#define NPH 13            // ceil(50000/4096)
#define PHSH 12           // phase = src >> 12
#define NCNT (NNODE * NPH)
#define SCAN_CHUNK 2048
#define CAST_BLOCKS 3125   // N*128/8/256
#define WCONV_BLOCKS 48    // (16+32)*256/256
#define AGG_BLOCKS 2048    // 8 blocks/CU persistent

typedef __attribute__((ext_vector_type(8))) short short8;   // 8 bf16 (4 VGPRs)
typedef __attribute__((ext_vector_type(4))) float f32x4;    // MFMA acc

__device__ __forceinline__ float bflo(unsigned int u) {
    union { unsigned int i; float f; } c;
    c.i = u << 16;
    return c.f;
}
__device__ __forceinline__ float bfhi(unsigned int u) {
    union { unsigned int i; float f; } c;
    c.i = u & 0xFFFF0000u;
    return c.f;
}
__device__ __forceinline__ unsigned short f2bf(float f) {
    __hip_bfloat16 h = __float2bfloat16(f);  // RTN
    return *reinterpret_cast<unsigned short*>(&h);
}
__device__ __forceinline__ unsigned int pk(float lo, float hi) {
    return (unsigned int)f2bf(lo) | ((unsigned int)f2bf(hi) << 16);
}

// ---- prep: cast x->bf16, repack W1/W2, count (dst,phase) degrees ---------
__global__ __launch_bounds__(256) void prep_kernel(
    const float* __restrict__ x, unsigned int* __restrict__ xb,
    const float* __restrict__ W1, unsigned short* __restrict__ Wf1,
    const float* __restrict__ W2, unsigned short* __restrict__ Wf2,
    const int* __restrict__ ei, int* __restrict__ counts, int E) {
    int b = blockIdx.x, t = threadIdx.x;
    if (b < CAST_BLOCKS) {            // x[50000][128] fp32 -> bf16
        int i = b * 256 + t;          // 8 floats per thread, exact fit
        const float4* xf = reinterpret_cast<const float4*>(x);
        float4 p = xf[2 * i], q = xf[2 * i + 1];
        uint4 o;
        o.x = pk(p.x, p.y); o.y = pk(p.z, p.w);
        o.z = pk(q.x, q.y); o.w = pk(q.z, q.w);
        reinterpret_cast<uint4*>(xb)[i] = o;
    } else if (b < CAST_BLOCKS + WCONV_BLOCKS) {
        // Wf[g][col][j]=bf16(W[f(8g+j)][col]); Wf2 permuted to match gemm1's
        // packed epilogue: f(k)=(k&~63)|((k&3)<<4)|((k>>2)&15).
        int idx = (b - CAST_BLOCKS) * 256 + t;
        const float* W;
        unsigned short* Wf;
        bool perm;
        if (idx < 16 * 256) { W = W1; Wf = Wf1; perm = false; }
        else { idx -= 16 * 256; W = W2; Wf = Wf2; perm = true; }
        int g = idx >> 8, c = idx & 255;
        unsigned short vals[8];
#pragma unroll
        for (int j = 0; j < 8; ++j) {
            int k = 8 * g + j;
            int f = perm ? ((k & ~63) | ((k & 3) << 4) | ((k >> 2) & 15)) : k;
            vals[j] = f2bf(W[(size_t)f * 256 + c]);
        }
        *reinterpret_cast<ushort4*>(&Wf[(size_t)idx * 8]) =
            make_ushort4(vals[0], vals[1], vals[2], vals[3]);
        *reinterpret_cast<ushort4*>(&Wf[(size_t)idx * 8 + 4]) =
            make_ushort4(vals[4], vals[5], vals[6], vals[7]);
    } else {                           // (dst, src-phase) count
        int e = (b - CAST_BLOCKS - WCONV_BLOCKS) * 256 + t;
        if (e < E) {
            int s = ei[e];
            int d = ei[E + e];
            atomicAdd(&counts[d * NPH + (s >> PHSH)], 1);
        }
    }
}

// ---- 3-level exclusive scan over NCNT=650000 counters -------------------
__global__ __launch_bounds__(256) void scan_part1(const int* __restrict__ counts,
                                                  int* __restrict__ bsum, int m) {
    __shared__ int ws[4];
    int b = blockIdx.x, t = threadIdx.x;
    int base = b * SCAN_CHUNK + t * 8;
    int s = 0;
#pragma unroll
    for (int j = 0; j < 8; ++j) {
        int i = base + j;
        if (i < m) s += counts[i];
    }
#pragma unroll
    for (int off = 32; off >= 1; off >>= 1) s += __shfl_xor(s, off, 64);
    if ((t & 63) == 0) ws[t >> 6] = s;
    __syncthreads();
    if (t == 0) bsum[b] = ws[0] + ws[1] + ws[2] + ws[3];
}

// single 64-thread block: serial-carry wave scan over nb block sums
__global__ void scan_part2(const int* __restrict__ bsum, int* __restrict__ boff,
                           int* __restrict__ row_ptr, int nb, int m) {
    int l = threadIdx.x;
    int carry = 0;
    for (int base = 0; base < nb; base += 64) {
        int i = base + l;
        int v = (i < nb) ? bsum[i] : 0;
        int incl = v;
#pragma unroll
        for (int off = 1; off < 64; off <<= 1) {
            int u = __shfl_up(incl, off, 64);
            if (l >= off) incl += u;
        }
        if (i < nb) boff[i] = carry + incl - v;
        carry += __shfl(incl, 63, 64);
    }
    if (l == 0) row_ptr[m] = carry;  // == E
}

__global__ __launch_bounds__(256) void scan_part3(const int* __restrict__ counts,
                                                  const int* __restrict__ boff,
                                                  int* __restrict__ row_ptr,
                                                  int* __restrict__ cursor, int m) {
    __shared__ int ws[4];
    int b = blockIdx.x, t = threadIdx.x, lane = t & 63, wid = t >> 6;
    int base = b * SCAN_CHUNK + t * 8;
    int v[8];
    int s = 0;
#pragma unroll
    for (int j = 0; j < 8; ++j) {
        int i = base + j;
        v[j] = (i < m) ? counts[i] : 0;
        s += v[j];
    }
    int incl = s;
#pragma unroll
    for (int off = 1; off < 64; off <<= 1) {
        int u = __shfl_up(incl, off, 64);
        if (lane >= off) incl += u;
    }
    if (lane == 63) ws[wid] = incl;
    __syncthreads();
    int woff = 0;
    for (int u = 0; u < wid; ++u) woff += ws[u];
    int ex = boff[b] + woff + incl - s;
#pragma unroll
    for (int j = 0; j < 8; ++j) {
        int i = base + j;
        if (i < m) { row_ptr[i] = ex; cursor[i] = ex; }
        ex += v[j];
    }
}

// dinv[i] = rsqrt(deg_i + 1); deg from scanned (node,phase) offsets
__global__ void dinv_kernel(const int* __restrict__ rowp, float* __restrict__ dinv, int n) {
    int i = blockIdx.x * blockDim.x + threadIdx.x;
    if (i < n) {
        int deg = rowp[(i + 1) * NPH] - rowp[i * NPH];
        dinv[i] = rsqrtf((float)(deg + 1));
    }
}

// edata[pos] = {src, dinv[src]*dinv[dst]}; pos bucketed by (dst, src-phase)
__global__ void fill_kernel(const int* __restrict__ ei, const float* __restrict__ dinv,
                            int* __restrict__ cursor, int2* __restrict__ edata, int E) {
    int e = blockIdx.x * blockDim.x + threadIdx.x;
    if (e < E) {
        int s = ei[e];
        int d = ei[E + e];
        int pos = atomicAdd(&cursor[d * NPH + (s >> PHSH)], 1);
        float nm = dinv[s] * dinv[d];
        edata[pos] = make_int2(s, __float_as_int(nm));
    }
}

// ---- agg1 (persistent): A1[i] = sum nm*xb[src] + dinv_i^2*xb[i] ---------
__global__ __launch_bounds__(256) void agg1_kernel(const unsigned int* __restrict__ xb,
                                                   const int* __restrict__ rowp,
                                                   const int2* __restrict__ edata,
                                                   const float* __restrict__ dinv,
                                                   unsigned int* __restrict__ A1, int n) {
    int wid = threadIdx.x >> 6;
    int lane = threadIdx.x & 63;
    for (int nb = blockIdx.x; nb * 4 < n; nb += AGG_BLOCKS) {
        int node = nb * 4 + wid;
        if (node >= n) continue;
        float di = dinv[node];
        float d2 = di * di;
        unsigned int sv = xb[(size_t)node * 64 + lane];
        float a0 = bflo(sv) * d2, a1 = bfhi(sv) * d2;
        int beg = rowp[node * NPH], end = rowp[node * NPH + NPH];
#pragma unroll 4
        for (int e = beg; e < end; ++e) {
            int2 ed = edata[e];
            float nm = __int_as_float(ed.y);
            unsigned int v = xb[(size_t)ed.x * 64 + lane];
            a0 = fmaf(bflo(v), nm, a0);
            a1 = fmaf(bfhi(v), nm, a1);
        }
        A1[(size_t)node * 64 + lane] = pk(a0, a1);
    }
}

// ---- agg2 (persistent): A2[i] = sum nm*hb[src] + dinv_i^2*hb[i] ---------
__global__ __launch_bounds__(256) void agg2_kernel(const uint2* __restrict__ hb,
                                                   const int* __restrict__ rowp,
                                                   const int2* __restrict__ edata,
                                                   const float* __restrict__ dinv,
                                                   uint2* __restrict__ A2, int n) {
    int wid = threadIdx.x >> 6;
    int lane = threadIdx.x & 63;
    for (int nb = blockIdx.x; nb * 4 < n; nb += AGG_BLOCKS) {
        int node = nb * 4 + wid;
        if (node >= n) continue;
        float di = dinv[node];
        float d2 = di * di;
        uint2 sv = hb[(size_t)node * 64 + lane];
        float a0 = bflo(sv.x) * d2, a1 = bfhi(sv.x) * d2;
        float a2 = bflo(sv.y) * d2, a3 = bfhi(sv.y) * d2;
        int beg = rowp[node * NPH], end = rowp[node * NPH + NPH];
#pragma unroll 4
        for (int e = beg; e < end; ++e) {
            int2 ed = edata[e];
            float nm = __int_as_float(ed.y);
            uint2 v = hb[(size_t)ed.x * 64 + lane];
            a0 = fmaf(bflo(v.x), nm, a0);
            a1 = fmaf(bfhi(v.x), nm, a1);
            a2 = fmaf(bflo(v.y), nm, a2);
            a3 = fmaf(bfhi(v.y), nm, a3);
        }
        uint2 o;
        o.x = pk(a0, a1);
        o.y = pk(a2, a3);
        A2[(size_t)node * 64 + lane] = o;
    }
}

// ---- MFMA GEMM + fused epilogue: out = f(A[n,K] @ W[K,256] + bias) ------
// BM=128, BN=256, 512 threads = 8 waves in 2x4; wave = 64x64.
// EPI 0: relu -> bf16 H in pi-permuted column order (packed uint2 stores).
// EPI 1: row L2-normalize -> f32 out (true order, nontemporal).
template <int K, int EPI>
__global__ __launch_bounds__(512) void gemm_fused(const unsigned short* __restrict__ A,
                                                  const unsigned short* __restrict__ Wf,
                                                  const float* __restrict__ bias,
                                                  void* __restrict__ outp, int n) {
    __shared__ unsigned short As[128 * K];
    __shared__ __align__(16) float ssred[128][4];
    int t = threadIdx.x;
    int row0 = blockIdx.x * 128;

#pragma unroll
    for (int i = 0; i < (128 * K) / (8 * 512); ++i) {
        int o = 8 * (t + 512 * i);
        int row = o / K, k = o % K;
        int srow = row0 + row;
        uint4 v = make_uint4(0u, 0u, 0u, 0u);
        if (srow < n) v = *reinterpret_cast<const uint4*>(&A[(size_t)srow * K + k]);
        int gx = (k >> 3) ^ (row & 7);
        *reinterpret_cast<uint4*>(&As[row * K + gx * 8]) = v;
    }
    __syncthreads();

    int lane = t & 63, wv = t >> 6;
    int rw = wv >> 2, cw = wv & 3;  // 2x4 waves
    int l15 = lane & 15, lhi = lane >> 4;
    f32x4 zero = {0.f, 0.f, 0.f, 0.f};
    f32x4 acc[4][4];
#pragma unroll
    for (int rf = 0; rf < 4; ++rf)
#pragma unroll
        for (int cf = 0; cf < 4; ++cf) acc[rf][cf] = zero;

#pragma unroll
    for (int s = 0; s < K / 32; ++s) {
        int g = 4 * s + lhi;
        short8 a[4], b[4];
#pragma unroll
        for (int rf = 0; rf < 4; ++rf) {
            int row = 64 * rw + 16 * rf + l15;
            a[rf] = *reinterpret_cast<const short8*>(&As[row * K + (g ^ (row & 7)) * 8]);
        }
#pragma unroll
        for (int cf = 0; cf < 4; ++cf) {
            int c = 64 * cw + 16 * cf + l15;
            b[cf] = *reinterpret_cast<const short8*>(&Wf[((size_t)g * 256 + c) * 8]);
        }
#pragma unroll
        for (int rf = 0; rf < 4; ++rf)
#pragma unroll
            for (int cf = 0; cf < 4; ++cf)
                acc[rf][cf] = __builtin_amdgcn_mfma_f32_16x16x32_bf16(a[rf], b[cf], acc[rf][cf], 0, 0, 0);
    }

    if constexpr (EPI == 0) {  // bias + relu -> bf16, pi-packed
        unsigned short* H = (unsigned short*)outp;
        float bv[4];
#pragma unroll
        for (int cf = 0; cf < 4; ++cf) bv[cf] = bias[64 * cw + 16 * cf + l15];
#pragma unroll
        for (int rf = 0; rf < 4; ++rf) {
#pragma unroll
            for (int j = 0; j < 4; ++j) {
                int row = row0 + 64 * rw + 16 * rf + 4 * lhi + j;
                if (row < n) {
                    float c0 = fmaxf(acc[rf][0][j] + bv[0], 0.f);
                    float c1 = fmaxf(acc[rf][1][j] + bv[1], 0.f);
                    float c2 = fmaxf(acc[rf][2][j] + bv[2], 0.f);
                    float c3 = fmaxf(acc[rf][3][j] + bv[3], 0.f);
                    uint2 o;
                    o.x = pk(c0, c1);
                    o.y = pk(c2, c3);
                    *reinterpret_cast<uint2*>(&H[(size_t)row * 256 + 64 * cw + 4 * l15]) = o;
                }
            }
        }
    } else {  // bias + row L2 normalize -> f32
        float* O = (float*)outp;
        float ss[4][4];
#pragma unroll
        for (int rf = 0; rf < 4; ++rf)
#pragma unroll
            for (int j = 0; j < 4; ++j) ss[rf][j] = 0.f;
#pragma unroll
        for (int cf = 0; cf < 4; ++cf) {
            int col = 64 * cw + 16 * cf + l15;
            float bc = bias[col];
#pragma unroll
            for (int rf = 0; rf < 4; ++rf)
#pragma unroll
                for (int j = 0; j < 4; ++j) {
                    float v = acc[rf][cf][j] + bc;
                    acc[rf][cf][j] = v;
                    ss[rf][j] = fmaf(v, v, ss[rf][j]);
                }
        }
#pragma unroll
        for (int rf = 0; rf < 4; ++rf)
#pragma unroll
            for (int j = 0; j < 4; ++j) {
#pragma unroll
                for (int off = 1; off <= 8; off <<= 1)
                    ss[rf][j] += __shfl_xor(ss[rf][j], off, 64);
            }
        if (l15 == 0) {
#pragma unroll
            for (int rf = 0; rf < 4; ++rf)
#pragma unroll
                for (int j = 0; j < 4; ++j)
                    ssred[64 * rw + 16 * rf + 4 * lhi + j][cw] = ss[rf][j];
        }
        __syncthreads();
        float rinv[4][4];
#pragma unroll
        for (int rf = 0; rf < 4; ++rf)
#pragma unroll
            for (int j = 0; j < 4; ++j) {
                float4 s4 = *reinterpret_cast<const float4*>(
                    ssred[64 * rw + 16 * rf + 4 * lhi + j]);
                float tot = s4.x + s4.y + s4.z + s4.w;
                rinv[rf][j] = 1.f / fmaxf(sqrtf(tot), 1e-12f);
            }
#pragma unroll
        for (int cf = 0; cf < 4; ++cf) {
            int col = 64 * cw + 16 * cf + l15;
#pragma unroll
            for (int rf = 0; rf < 4; ++rf)
#pragma unroll
                for (int j = 0; j < 4; ++j) {
                    int row = row0 + 64 * rw + 16 * rf + 4 * lhi + j;
                    if (row < n)
                        __builtin_nontemporal_store(acc[rf][cf][j] * rinv[rf][j],
                                                    &O[(size_t)row * 256 + col]);
                }
        }
    }
}

extern "C" void kernel_launch(void* const* d_in, const int* in_sizes, int n_in,
                              void* d_out, int out_size, void* d_ws, size_t ws_size,
                              hipStream_t stream) {
    const float* x  = (const float*)d_in[0];
    const int*   ei = (const int*)d_in[1];
    const float* W1 = (const float*)d_in[2];
    const float* b1 = (const float*)d_in[3];
    const float* W2 = (const float*)d_in[4];
    const float* b2 = (const float*)d_in[5];
    float* out = (float*)d_out;

    const int N = NNODE;
    const int E = in_sizes[1] / 2;
    const int M = NCNT;                                   // 650000 counters
    const int NB = (M + SCAN_CHUNK - 1) / SCAN_CHUNK;     // 318

    char* ws = (char*)d_ws;
    size_t off = 0;
    auto alloc = [&](size_t bytes) -> void* {
        void* p = ws + off;
        off = (off + bytes + 255) & ~(size_t)255;
        return p;
    };
    unsigned int*   xb  = (unsigned int*)alloc((size_t)N * 128 * 2);    // x bf16
    unsigned int*   A1  = (unsigned int*)alloc((size_t)N * 128 * 2);    // agg(x)
    unsigned short* Bbf = (unsigned short*)alloc((size_t)N * FDIM * 2); // relu(gcn1), pi-order
    uint2*          A2  = (uint2*)alloc((size_t)N * FDIM * 2);          // agg(H1), pi-order
    unsigned short* Wf1 = (unsigned short*)alloc((size_t)16 * 256 * 8 * 2);
    unsigned short* Wf2 = (unsigned short*)alloc((size_t)32 * 256 * 8 * 2);
    int*   counts = (int*)alloc((size_t)M * 4);
    int*   rowp   = (int*)alloc((size_t)(M + 1) * 4);
    int*   cursor = (int*)alloc((size_t)M * 4);
    float* dinv   = (float*)alloc((size_t)N * 4);
    int2*  edata  = (int2*)alloc((size_t)E * 8);
    int*   bsum   = (int*)alloc((size_t)NB * 4);
    int*   boff   = (int*)alloc((size_t)NB * 4);

    hipMemsetAsync(counts, 0, (size_t)M * 4, stream);
    int count_blocks = (E + 255) / 256;
    prep_kernel<<<CAST_BLOCKS + WCONV_BLOCKS + count_blocks, 256, 0, stream>>>(
        x, xb, W1, Wf1, W2, Wf2, ei, counts, E);
    scan_part1<<<NB, 256, 0, stream>>>(counts, bsum, M);
    scan_part2<<<1, 64, 0, stream>>>(bsum, boff, rowp, NB, M);
    scan_part3<<<NB, 256, 0, stream>>>(counts, boff, rowp, cursor, M);
    dinv_kernel<<<(N + 255) / 256, 256, 0, stream>>>(rowp, dinv, N);
    fill_kernel<<<(E + 255) / 256, 256, 0, stream>>>(ei, dinv, cursor, edata, E);

    agg1_kernel<<<AGG_BLOCKS, 256, 0, stream>>>(xb, rowp, edata, dinv, A1, N);
    gemm_fused<128, 0><<<(N + 127) / 128, 512, 0, stream>>>(
        (const unsigned short*)A1, Wf1, b1, Bbf, N);
    agg2_kernel<<<AGG_BLOCKS, 256, 0, stream>>>(
        (const uint2*)Bbf, rowp, edata, dinv, A2, N);
    gemm_fused<256, 1><<<(N + 127) / 128, 512, 0, stream>>>(
        (const unsigned short*)A2, Wf2, b2, out, N);
}

// Round 16
// 236.901 us; speedup vs baseline: 1.0121x; 1.0121x over previous
//
#include <hip/hip_runtime.h>
#include <hip/hip_bf16.h>

// GCN encoder: 2x GCNConv (sym-norm, self-loops) + ReLU + row L2 normalize.
// N=50000, E=800000, IN=128, HID=256, OUT=256.
// BEST CONFIG (r14): aggregate-first + phase-sorted edata, r3-form aggs
// (wave/node, unroll-4, cached loads), BM=128 512-thread MFMA GEMMs with
// fused epilogues, pi-permuted H1 columns.
// Measured floor notes: agg is gather-latency-bound (~59us/410MB); nt loads,
// dual-wave, persistent grid, col-only CSR all measured worse (r6-r15).

#define NNODE 50000
#define FDIM 256
#define NPH 13            // ceil(50000/4096)
#define PHSH 12           // phase = src >> 12
#define NCNT (NNODE * NPH)
#define SCAN_CHUNK 2048
#define CAST_BLOCKS 3125   // N*128/8/256
#define WCONV_BLOCKS 48    // (16+32)*256/256

typedef __attribute__((ext_vector_type(8))) short short8;   // 8 bf16 (4 VGPRs)
typedef __attribute__((ext_vector_type(4))) float f32x4;    // MFMA acc

__device__ __forceinline__ float bflo(unsigned int u) {
    union { unsigned int i; float f; } c;
    c.i = u << 16;
    return c.f;
}
__device__ __forceinline__ float bfhi(unsigned int u) {
    union { unsigned int i; float f; } c;
    c.i = u & 0xFFFF0000u;
    return c.f;
}
__device__ __forceinline__ unsigned short f2bf(float f) {
    __hip_bfloat16 h = __float2bfloat16(f);  // RTN
    return *reinterpret_cast<unsigned short*>(&h);
}
__device__ __forceinline__ unsigned int pk(float lo, float hi) {
    return (unsigned int)f2bf(lo) | ((unsigned int)f2bf(hi) << 16);
}

// ---- prep: cast x->bf16, repack W1/W2, count (dst,phase) degrees ---------
__global__ __launch_bounds__(256) void prep_kernel(
    const float* __restrict__ x, unsigned int* __restrict__ xb,
    const float* __restrict__ W1, unsigned short* __restrict__ Wf1,
    const float* __restrict__ W2, unsigned short* __restrict__ Wf2,
    const int* __restrict__ ei, int* __restrict__ counts, int E) {
    int b = blockIdx.x, t = threadIdx.x;
    if (b < CAST_BLOCKS) {            // x[50000][128] fp32 -> bf16
        int i = b * 256 + t;          // 8 floats per thread, exact fit
        const float4* xf = reinterpret_cast<const float4*>(x);
        float4 p = xf[2 * i], q = xf[2 * i + 1];
        uint4 o;
        o.x = pk(p.x, p.y); o.y = pk(p.z, p.w);
        o.z = pk(q.x, q.y); o.w = pk(q.z, q.w);
        reinterpret_cast<uint4*>(xb)[i] = o;
    } else if (b < CAST_BLOCKS + WCONV_BLOCKS) {
        // Wf[g][col][j]=bf16(W[f(8g+j)][col]); Wf2 permuted to match gemm1's
        // packed epilogue: f(k)=(k&~63)|((k&3)<<4)|((k>>2)&15).
        int idx = (b - CAST_BLOCKS) * 256 + t;
        const float* W;
        unsigned short* Wf;
        bool perm;
        if (idx < 16 * 256) { W = W1; Wf = Wf1; perm = false; }
        else { idx -= 16 * 256; W = W2; Wf = Wf2; perm = true; }
        int g = idx >> 8, c = idx & 255;
        unsigned short vals[8];
#pragma unroll
        for (int j = 0; j < 8; ++j) {
            int k = 8 * g + j;
            int f = perm ? ((k & ~63) | ((k & 3) << 4) | ((k >> 2) & 15)) : k;
            vals[j] = f2bf(W[(size_t)f * 256 + c]);
        }
        *reinterpret_cast<ushort4*>(&Wf[(size_t)idx * 8]) =
            make_ushort4(vals[0], vals[1], vals[2], vals[3]);
        *reinterpret_cast<ushort4*>(&Wf[(size_t)idx * 8 + 4]) =
            make_ushort4(vals[4], vals[5], vals[6], vals[7]);
    } else {                           // (dst, src-phase) count
        int e = (b - CAST_BLOCKS - WCONV_BLOCKS) * 256 + t;
        if (e < E) {
            int s = ei[e];
            int d = ei[E + e];
            atomicAdd(&counts[d * NPH + (s >> PHSH)], 1);
        }
    }
}

// ---- 3-level exclusive scan over NCNT=650000 counters -------------------
__global__ __launch_bounds__(256) void scan_part1(const int* __restrict__ counts,
                                                  int* __restrict__ bsum, int m) {
    __shared__ int ws[4];
    int b = blockIdx.x, t = threadIdx.x;
    int base = b * SCAN_CHUNK + t * 8;
    int s = 0;
#pragma unroll
    for (int j = 0; j < 8; ++j) {
        int i = base + j;
        if (i < m) s += counts[i];
    }
#pragma unroll
    for (int off = 32; off >= 1; off >>= 1) s += __shfl_xor(s, off, 64);
    if ((t & 63) == 0) ws[t >> 6] = s;
    __syncthreads();
    if (t == 0) bsum[b] = ws[0] + ws[1] + ws[2] + ws[3];
}

// single 64-thread block: serial-carry wave scan over nb block sums
__global__ void scan_part2(const int* __restrict__ bsum, int* __restrict__ boff,
                           int* __restrict__ row_ptr, int nb, int m) {
    int l = threadIdx.x;
    int carry = 0;
    for (int base = 0; base < nb; base += 64) {
        int i = base + l;
        int v = (i < nb) ? bsum[i] : 0;
        int incl = v;
#pragma unroll
        for (int off = 1; off < 64; off <<= 1) {
            int u = __shfl_up(incl, off, 64);
            if (l >= off) incl += u;
        }
        if (i < nb) boff[i] = carry + incl - v;
        carry += __shfl(incl, 63, 64);
    }
    if (l == 0) row_ptr[m] = carry;  // == E
}

__global__ __launch_bounds__(256) void scan_part3(const int* __restrict__ counts,
                                                  const int* __restrict__ boff,
                                                  int* __restrict__ row_ptr,
                                                  int* __restrict__ cursor, int m) {
    __shared__ int ws[4];
    int b = blockIdx.x, t = threadIdx.x, lane = t & 63, wid = t >> 6;
    int base = b * SCAN_CHUNK + t * 8;
    int v[8];
    int s = 0;
#pragma unroll
    for (int j = 0; j < 8; ++j) {
        int i = base + j;
        v[j] = (i < m) ? counts[i] : 0;
        s += v[j];
    }
    int incl = s;
#pragma unroll
    for (int off = 1; off < 64; off <<= 1) {
        int u = __shfl_up(incl, off, 64);
        if (lane >= off) incl += u;
    }
    if (lane == 63) ws[wid] = incl;
    __syncthreads();
    int woff = 0;
    for (int u = 0; u < wid; ++u) woff += ws[u];
    int ex = boff[b] + woff + incl - s;
#pragma unroll
    for (int j = 0; j < 8; ++j) {
        int i = base + j;
        if (i < m) { row_ptr[i] = ex; cursor[i] = ex; }
        ex += v[j];
    }
}

// dinv[i] = rsqrt(deg_i + 1); deg from scanned (node,phase) offsets
__global__ void dinv_kernel(const int* __restrict__ rowp, float* __restrict__ dinv, int n) {
    int i = blockIdx.x * blockDim.x + threadIdx.x;
    if (i < n) {
        int deg = rowp[(i + 1) * NPH] - rowp[i * NPH];
        dinv[i] = rsqrtf((float)(deg + 1));
    }
}

// edata[pos] = {src, dinv[src]*dinv[dst]}; pos bucketed by (dst, src-phase)
__global__ void fill_kernel(const int* __restrict__ ei, const float* __restrict__ dinv,
                            int* __restrict__ cursor, int2* __restrict__ edata, int E) {
    int e = blockIdx.x * blockDim.x + threadIdx.x;
    if (e < E) {
        int s = ei[e];
        int d = ei[E + e];
        int pos = atomicAdd(&cursor[d * NPH + (s >> PHSH)], 1);
        float nm = dinv[s] * dinv[d];
        edata[pos] = make_int2(s, __float_as_int(nm));
    }
}

// ---- agg1: A1[i] = sum nm*xb[src] + dinv_i^2*xb[i]  (128 feats, 256B rows)
__global__ __launch_bounds__(256) void agg1_kernel(const unsigned int* __restrict__ xb,
                                                   const int* __restrict__ rowp,
                                                   const int2* __restrict__ edata,
                                                   const float* __restrict__ dinv,
                                                   unsigned int* __restrict__ A1, int n) {
    int node = (blockIdx.x * blockDim.x + threadIdx.x) >> 6;
    int lane = threadIdx.x & 63;
    if (node >= n) return;
    float di = dinv[node];
    float d2 = di * di;
    unsigned int sv = xb[(size_t)node * 64 + lane];
    float a0 = bflo(sv) * d2, a1 = bfhi(sv) * d2;
    int beg = rowp[node * NPH], end = rowp[node * NPH + NPH];
#pragma unroll 4
    for (int e = beg; e < end; ++e) {
        int2 ed = edata[e];
        float nm = __int_as_float(ed.y);
        unsigned int v = xb[(size_t)ed.x * 64 + lane];
        a0 = fmaf(bflo(v), nm, a0);
        a1 = fmaf(bfhi(v), nm, a1);
    }
    A1[(size_t)node * 64 + lane] = pk(a0, a1);
}

// ---- agg2: A2[i] = sum nm*hb[src] + dinv_i^2*hb[i]  (256 feats, 512B rows)
__global__ __launch_bounds__(256) void agg2_kernel(const uint2* __restrict__ hb,
                                                   const int* __restrict__ rowp,
                                                   const int2* __restrict__ edata,
                                                   const float* __restrict__ dinv,
                                                   uint2* __restrict__ A2, int n) {
    int node = (blockIdx.x * blockDim.x + threadIdx.x) >> 6;
    int lane = threadIdx.x & 63;
    if (node >= n) return;
    float di = dinv[node];
    float d2 = di * di;
    uint2 sv = hb[(size_t)node * 64 + lane];
    float a0 = bflo(sv.x) * d2, a1 = bfhi(sv.x) * d2;
    float a2 = bflo(sv.y) * d2, a3 = bfhi(sv.y) * d2;
    int beg = rowp[node * NPH], end = rowp[node * NPH + NPH];
#pragma unroll 4
    for (int e = beg; e < end; ++e) {
        int2 ed = edata[e];
        float nm = __int_as_float(ed.y);
        uint2 v = hb[(size_t)ed.x * 64 + lane];
        a0 = fmaf(bflo(v.x), nm, a0);
        a1 = fmaf(bfhi(v.x), nm, a1);
        a2 = fmaf(bflo(v.y), nm, a2);
        a3 = fmaf(bfhi(v.y), nm, a3);
    }
    uint2 o;
    o.x = pk(a0, a1);
    o.y = pk(a2, a3);
    A2[(size_t)node * 64 + lane] = o;
}

// ---- MFMA GEMM + fused epilogue: out = f(A[n,K] @ W[K,256] + bias) ------
// BM=128, BN=256, 512 threads = 8 waves in 2x4; wave = 64x64.
// EPI 0: relu -> bf16 H in pi-permuted column order (packed uint2 stores).
// EPI 1: row L2-normalize -> f32 out (true order, nontemporal).
template <int K, int EPI>
__global__ __launch_bounds__(512) void gemm_fused(const unsigned short* __restrict__ A,
                                                  const unsigned short* __restrict__ Wf,
                                                  const float* __restrict__ bias,
                                                  void* __restrict__ outp, int n) {
    __shared__ unsigned short As[128 * K];
    __shared__ __align__(16) float ssred[128][4];
    int t = threadIdx.x;
    int row0 = blockIdx.x * 128;

#pragma unroll
    for (int i = 0; i < (128 * K) / (8 * 512); ++i) {
        int o = 8 * (t + 512 * i);
        int row = o / K, k = o % K;
        int srow = row0 + row;
        uint4 v = make_uint4(0u, 0u, 0u, 0u);
        if (srow < n) v = *reinterpret_cast<const uint4*>(&A[(size_t)srow * K + k]);
        int gx = (k >> 3) ^ (row & 7);
        *reinterpret_cast<uint4*>(&As[row * K + gx * 8]) = v;
    }
    __syncthreads();

    int lane = t & 63, wv = t >> 6;
    int rw = wv >> 2, cw = wv & 3;  // 2x4 waves
    int l15 = lane & 15, lhi = lane >> 4;
    f32x4 zero = {0.f, 0.f, 0.f, 0.f};
    f32x4 acc[4][4];
#pragma unroll
    for (int rf = 0; rf < 4; ++rf)
#pragma unroll
        for (int cf = 0; cf < 4; ++cf) acc[rf][cf] = zero;

#pragma unroll
    for (int s = 0; s < K / 32; ++s) {
        int g = 4 * s + lhi;
        short8 a[4], b[4];
#pragma unroll
        for (int rf = 0; rf < 4; ++rf) {
            int row = 64 * rw + 16 * rf + l15;
            a[rf] = *reinterpret_cast<const short8*>(&As[row * K + (g ^ (row & 7)) * 8]);
        }
#pragma unroll
        for (int cf = 0; cf < 4; ++cf) {
            int c = 64 * cw + 16 * cf + l15;
            b[cf] = *reinterpret_cast<const short8*>(&Wf[((size_t)g * 256 + c) * 8]);
        }
#pragma unroll
        for (int rf = 0; rf < 4; ++rf)
#pragma unroll
            for (int cf = 0; cf < 4; ++cf)
                acc[rf][cf] = __builtin_amdgcn_mfma_f32_16x16x32_bf16(a[rf], b[cf], acc[rf][cf], 0, 0, 0);
    }

    if constexpr (EPI == 0) {  // bias + relu -> bf16, pi-packed
        unsigned short* H = (unsigned short*)outp;
        float bv[4];
#pragma unroll
        for (int cf = 0; cf < 4; ++cf) bv[cf] = bias[64 * cw + 16 * cf + l15];
#pragma unroll
        for (int rf = 0; rf < 4; ++rf) {
#pragma unroll
            for (int j = 0; j < 4; ++j) {
                int row = row0 + 64 * rw + 16 * rf + 4 * lhi + j;
                if (row < n) {
                    float c0 = fmaxf(acc[rf][0][j] + bv[0], 0.f);
                    float c1 = fmaxf(acc[rf][1][j] + bv[1], 0.f);
                    float c2 = fmaxf(acc[rf][2][j] + bv[2], 0.f);
                    float c3 = fmaxf(acc[rf][3][j] + bv[3], 0.f);
                    uint2 o;
                    o.x = pk(c0, c1);
                    o.y = pk(c2, c3);
                    *reinterpret_cast<uint2*>(&H[(size_t)row * 256 + 64 * cw + 4 * l15]) = o;
                }
            }
        }
    } else {  // bias + row L2 normalize -> f32
        float* O = (float*)outp;
        float ss[4][4];
#pragma unroll
        for (int rf = 0; rf < 4; ++rf)
#pragma unroll
            for (int j = 0; j < 4; ++j) ss[rf][j] = 0.f;
#pragma unroll
        for (int cf = 0; cf < 4; ++cf) {
            int col = 64 * cw + 16 * cf + l15;
            float bc = bias[col];
#pragma unroll
            for (int rf = 0; rf < 4; ++rf)
#pragma unroll
                for (int j = 0; j < 4; ++j) {
                    float v = acc[rf][cf][j] + bc;
                    acc[rf][cf][j] = v;
                    ss[rf][j] = fmaf(v, v, ss[rf][j]);
                }
        }
#pragma unroll
        for (int rf = 0; rf < 4; ++rf)
#pragma unroll
            for (int j = 0; j < 4; ++j) {
#pragma unroll
                for (int off = 1; off <= 8; off <<= 1)
                    ss[rf][j] += __shfl_xor(ss[rf][j], off, 64);
            }
        if (l15 == 0) {
#pragma unroll
            for (int rf = 0; rf < 4; ++rf)
#pragma unroll
                for (int j = 0; j < 4; ++j)
                    ssred[64 * rw + 16 * rf + 4 * lhi + j][cw] = ss[rf][j];
        }
        __syncthreads();
        float rinv[4][4];
#pragma unroll
        for (int rf = 0; rf < 4; ++rf)
#pragma unroll
            for (int j = 0; j < 4; ++j) {
                float4 s4 = *reinterpret_cast<const float4*>(
                    ssred[64 * rw + 16 * rf + 4 * lhi + j]);
                float tot = s4.x + s4.y + s4.z + s4.w;
                rinv[rf][j] = 1.f / fmaxf(sqrtf(tot), 1e-12f);
            }
#pragma unroll
        for (int cf = 0; cf < 4; ++cf) {
            int col = 64 * cw + 16 * cf + l15;
#pragma unroll
            for (int rf = 0; rf < 4; ++rf)
#pragma unroll
                for (int j = 0; j < 4; ++j) {
                    int row = row0 + 64 * rw + 16 * rf + 4 * lhi + j;
                    if (row < n)
                        __builtin_nontemporal_store(acc[rf][cf][j] * rinv[rf][j],
                                                    &O[(size_t)row * 256 + col]);
                }
        }
    }
}

extern "C" void kernel_launch(void* const* d_in, const int* in_sizes, int n_in,
                              void* d_out, int out_size, void* d_ws, size_t ws_size,
                              hipStream_t stream) {
    const float* x  = (const float*)d_in[0];
    const int*   ei = (const int*)d_in[1];
    const float* W1 = (const float*)d_in[2];
    const float* b1 = (const float*)d_in[3];
    const float* W2 = (const float*)d_in[4];
    const float* b2 = (const float*)d_in[5];
    float* out = (float*)d_out;

    const int N = NNODE;
    const int E = in_sizes[1] / 2;
    const int M = NCNT;                                   // 650000 counters
    const int NB = (M + SCAN_CHUNK - 1) / SCAN_CHUNK;     // 318

    char* ws = (char*)d_ws;
    size_t off = 0;
    auto alloc = [&](size_t bytes) -> void* {
        void* p = ws + off;
        off = (off + bytes + 255) & ~(size_t)255;
        return p;
    };
    unsigned int*   xb  = (unsigned int*)alloc((size_t)N * 128 * 2);    // x bf16
    unsigned int*   A1  = (unsigned int*)alloc((size_t)N * 128 * 2);    // agg(x)
    unsigned short* Bbf = (unsigned short*)alloc((size_t)N * FDIM * 2); // relu(gcn1), pi-order
    uint2*          A2  = (uint2*)alloc((size_t)N * FDIM * 2);          // agg(H1), pi-order
    unsigned short* Wf1 = (unsigned short*)alloc((size_t)16 * 256 * 8 * 2);
    unsigned short* Wf2 = (unsigned short*)alloc((size_t)32 * 256 * 8 * 2);
    int*   counts = (int*)alloc((size_t)M * 4);
    int*   rowp   = (int*)alloc((size_t)(M + 1) * 4);
    int*   cursor = (int*)alloc((size_t)M * 4);
    float* dinv   = (float*)alloc((size_t)N * 4);
    int2*  edata  = (int2*)alloc((size_t)E * 8);
    int*   bsum   = (int*)alloc((size_t)NB * 4);
    int*   boff   = (int*)alloc((size_t)NB * 4);

    hipMemsetAsync(counts, 0, (size_t)M * 4, stream);
    int count_blocks = (E + 255) / 256;
    prep_kernel<<<CAST_BLOCKS + WCONV_BLOCKS + count_blocks, 256, 0, stream>>>(
        x, xb, W1, Wf1, W2, Wf2, ei, counts, E);
    scan_part1<<<NB, 256, 0, stream>>>(counts, bsum, M);
    scan_part2<<<1, 64, 0, stream>>>(bsum, boff, rowp, NB, M);
    scan_part3<<<NB, 256, 0, stream>>>(counts, boff, rowp, cursor, M);
    dinv_kernel<<<(N + 255) / 256, 256, 0, stream>>>(rowp, dinv, N);
    fill_kernel<<<(E + 255) / 256, 256, 0, stream>>>(ei, dinv, cursor, edata, E);

    agg1_kernel<<<(N * 64 + 255) / 256, 256, 0, stream>>>(xb, rowp, edata, dinv, A1, N);
    gemm_fused<128, 0><<<(N + 127) / 128, 512, 0, stream>>>(
        (const unsigned short*)A1, Wf1, b1, Bbf, N);
    agg2_kernel<<<(N * 64 + 255) / 256, 256, 0, stream>>>(
        (const uint2*)Bbf, rowp, edata, dinv, A2, N);
    gemm_fused<256, 1><<<(N + 127) / 128, 512, 0, stream>>>(
        (const unsigned short*)A2, Wf2, b2, out, N);
}